// Round 4
// baseline (524.344 us; speedup 1.0000x reference)
//
#include <hip/hip_runtime.h>
#include <hip/hip_bf16.h>
#include <math.h>

typedef __bf16 bf16_t;
typedef __bf16 bf16x4 __attribute__((ext_vector_type(4)));
typedef __bf16 bf16x8 __attribute__((ext_vector_type(8)));
typedef float f32x4 __attribute__((ext_vector_type(4)));

#define NB 2
#define NH 16
#define SEQ 2048
#define HD 64
#define DMODEL 1024
#define QK_SCALE 0.125f
#define LOG2E 1.44269504088896340f
#define INV_2PI 0.15915494309189535f

__device__ __forceinline__ bf16_t to_bf16(float x) { return (bf16_t)x; }
#define MFMA16 __builtin_amdgcn_mfma_f32_16x16x32_bf16

// async 16B/lane global->LDS. LDS dest = base + lane*16 (wave-uniform base).
__device__ __forceinline__ void async_copy16(const bf16_t* g, bf16_t* l) {
  typedef const unsigned int __attribute__((address_space(1)))* gp_t;
  typedef unsigned int __attribute__((address_space(3)))* lp_t;
  __builtin_amdgcn_global_load_lds((gp_t)g, (lp_t)l, 16, 0, 0);
}

// ---------------------------------------------------------------------------
// K1: RoPE(q,k) + cast to bf16 + layout packs (unchanged from R3).
// ---------------------------------------------------------------------------
__global__ __launch_bounds__(256) void k1_rope_pack(
    const float* __restrict__ q, const float* __restrict__ k, const float* __restrict__ v,
    bf16_t* __restrict__ qrT, bf16_t* __restrict__ krN, bf16_t* __restrict__ vT)
{
  __shared__ bf16_t tile[64][65];
  const int tid = threadIdx.x;
  const int blk = blockIdx.x;
  const int st = blk & 31;
  const int bh = blk >> 5;
  const int s0 = st * 64;

  const size_t base_sd = ((size_t)bh * SEQ + s0) * HD;
  const float* qb = q + base_sd;
  const float* kb = k + base_sd;
  const float* vb = v + base_sd;
  bf16_t* qrTb = qrT + (size_t)bh * HD * SEQ;
  bf16_t* krNb = krN + base_sd;
  bf16_t* vTb  = vT  + (size_t)bh * HD * SEQ;

  #pragma unroll
  for (int pp = 0; pp < 8; ++pp) {
    int idx = pp * 256 + tid;
    int sr = idx >> 5;
    int j  = idx & 31;
    float freq = __builtin_amdgcn_exp2f(-(float)j * (13.287712379549449f / 32.0f));
    float ang = (float)(s0 + sr) * freq;
    float rev = ang * INV_2PI;
    rev = rev - floorf(rev);
    float c  = __builtin_amdgcn_cosf(rev);
    float sn = __builtin_amdgcn_sinf(rev);
    float q1 = qb[sr*HD + j], q2 = qb[sr*HD + j + 32];
    tile[sr][j]      = to_bf16((q1*c - q2*sn) * QK_SCALE);
    tile[sr][j + 32] = to_bf16((q2*c + q1*sn) * QK_SCALE);
    float ka = kb[sr*HD + j], kbv = kb[sr*HD + j + 32];
    krNb[sr*HD + j]      = to_bf16(ka*c - kbv*sn);
    krNb[sr*HD + j + 32] = to_bf16(kbv*c + ka*sn);
  }
  __syncthreads();
  #pragma unroll
  for (int c = 0; c < 2; ++c) {
    int id = c*256 + tid;
    int d = id >> 3;
    int sc = (id & 7) * 8;
    bf16x8 vec;
    #pragma unroll
    for (int i = 0; i < 8; ++i) vec[i] = tile[sc + i][d];
    *(bf16x8*)&qrTb[(size_t)d * SEQ + s0 + sc] = vec;
  }
  __syncthreads();
  #pragma unroll
  for (int c = 0; c < 4; ++c) {
    int id = c*256 + tid;
    int sr = id >> 4;
    int c4 = (id & 15) * 4;
    float4 v4 = *(const float4*)&vb[sr*HD + c4];
    tile[sr][c4+0] = to_bf16(v4.x);
    tile[sr][c4+1] = to_bf16(v4.y);
    tile[sr][c4+2] = to_bf16(v4.z);
    tile[sr][c4+3] = to_bf16(v4.w);
  }
  __syncthreads();
  #pragma unroll
  for (int c = 0; c < 2; ++c) {
    int id = c*256 + tid;
    int d = id >> 3;
    int sc = (id & 7) * 8;
    bf16x8 vec;
    #pragma unroll
    for (int i = 0; i < 8; ++i) vec[i] = tile[sc + i][d];
    *(bf16x8*)&vTb[(size_t)d * SEQ + s0 + sc] = vec;
  }
}

// ---------------------------------------------------------------------------
// K2: qt^T = qr^T x W^T per head. n-tile 32 (grid 1024). Double-buffered LDS,
// ONE barrier/iter. A via async global_load_lds (XOR-swizzled), W via VGPR
// prefetch distance 2 (+fp32->bf16 cvt). Output scaled by LOG2E.
// ---------------------------------------------------------------------------
__global__ __launch_bounds__(256) void k2_qt_gemm(
    const float* __restrict__ Wm,      // [NH][SEQ][SEQ] fp32
    const bf16_t* __restrict__ qrT,    // [b][h][d][s]
    bf16_t* __restrict__ qtT)          // [b][h][d][s]  (x LOG2E)
{
  __shared__ __align__(16) bf16_t A_lds[2][2][4096];  // [buf][batch][64r x 8chunk swz]
  __shared__ __align__(16) bf16_t W_lds[2][32*68];    // [buf][32 rows pitch 68]
  const int tid = threadIdx.x;
  const int blk = blockIdx.x;         // h*64 + ntile
  const int n0 = (blk & 63) * 32;
  const int h = blk >> 6;
  const int wave = tid >> 6, lane = tid & 63;
  const int l15 = lane & 15, quad = lane >> 4;
  const int rs = tid >> 3, cs = (tid & 7) * 8;   // W staging: 32 rows x 64 cols
  const int b2w = wave >> 1, jbase = (wave & 1) * 4;

  const float* Wh = Wm + (size_t)h * SEQ * SEQ + (size_t)n0 * SEQ;
  const bf16_t* Abase = qrT + (((size_t)b2w * NH + h) * HD) * SEQ;

  float4 wreg[2][2];

  // stage A tile (both batches; this wave handles batch b2w, 4 asyncs)
  #define STAGE_A(kb, bufIdx)                                                  \
    {                                                                          \
      _Pragma("unroll")                                                        \
      for (int j2 = 0; j2 < 4; ++j2) {                                         \
        int j = jbase + j2;                                                    \
        int r = j*8 + (lane >> 3);                                             \
        int sc = (lane & 7) ^ (r & 7);                                         \
        async_copy16(Abase + (size_t)r*SEQ + (kb) + sc*8,                      \
                     &A_lds[bufIdx][b2w][j*512]);                              \
      }                                                                        \
    }
  #define LOAD_W(kb, setIdx)                                                   \
    {                                                                          \
      wreg[setIdx][0] = *(const float4*)&Wh[(size_t)rs*SEQ + (kb) + cs];       \
      wreg[setIdx][1] = *(const float4*)&Wh[(size_t)rs*SEQ + (kb) + cs + 4];   \
    }
  #define STORE_W(setIdx, bufIdx)                                              \
    {                                                                          \
      bf16x8 wb;                                                               \
      float4 wa = wreg[setIdx][0], wc = wreg[setIdx][1];                       \
      wb[0]=to_bf16(wa.x); wb[1]=to_bf16(wa.y); wb[2]=to_bf16(wa.z);           \
      wb[3]=to_bf16(wa.w); wb[4]=to_bf16(wc.x); wb[5]=to_bf16(wc.y);           \
      wb[6]=to_bf16(wc.z); wb[7]=to_bf16(wc.w);                                \
      *(bf16x8*)&W_lds[bufIdx][rs*68 + cs] = wb;                               \
    }

  // prologue: tile 0 into buf0; W[1] into set1
  LOAD_W(0, 0);
  STAGE_A(0, 0);
  STORE_W(0, 0);
  LOAD_W(64, 1);
  __syncthreads();

  f32x4 acc[2][2] = {};

  for (int it = 0; it < 32; ++it) {
    const int buf = it & 1;
    if (it + 2 < 32) LOAD_W((it+2)*64, it & 1);
    if (it + 1 < 32) STAGE_A((it+1)*64, buf ^ 1);
    #pragma unroll
    for (int kc = 0; kc < 2; ++kc) {
      bf16x8 bfr[2];
      #pragma unroll
      for (int nt = 0; nt < 2; ++nt)
        bfr[nt] = *(const bf16x8*)&W_lds[buf][(nt*16 + l15)*68 + kc*32 + quad*8];
      #pragma unroll
      for (int b2 = 0; b2 < 2; ++b2) {
        int r = wave*16 + l15;
        bf16x8 af = *(const bf16x8*)&A_lds[buf][b2][r*64 + (((kc*4+quad) ^ (l15&7))*8)];
        #pragma unroll
        for (int nt = 0; nt < 2; ++nt)
          acc[b2][nt] = MFMA16(af, bfr[nt], acc[b2][nt], 0, 0, 0);
      }
    }
    if (it + 1 < 32) STORE_W((it+1) & 1, buf ^ 1);
    __syncthreads();
  }

  #pragma unroll
  for (int b2 = 0; b2 < 2; ++b2)
    #pragma unroll
    for (int nt = 0; nt < 2; ++nt)
      #pragma unroll
      for (int r = 0; r < 4; ++r) {
        int d = wave*16 + quad*4 + r;
        qtT[(((size_t)b2*NH + h)*HD + d)*SEQ + n0 + nt*16 + l15] =
            to_bf16(acc[b2][nt][r] * LOG2E);
      }
  #undef STAGE_A
  #undef LOAD_W
  #undef STORE_W
}

// ---------------------------------------------------------------------------
// K3: attention. q-tile 64/block; wave w: q-half (w&1), KEY-half (w>>1) —
// no-max softmax makes key-split partial O,L exactly additive. K/V staged by
// async global_load_lds, XOR-swizzled, double-buffered, ONE barrier/iter.
// ---------------------------------------------------------------------------
__global__ __launch_bounds__(256, 2) void k3_flash(
    const bf16_t* __restrict__ qtT,    // [b][h][d][s] (x LOG2E, x QK_SCALE)
    const bf16_t* __restrict__ krN,    // [b][h][s][d]
    const bf16_t* __restrict__ vT,     // [b][h][d][s]
    bf16_t* __restrict__ ctx)          // [b][s][DMODEL]
{
  __shared__ __align__(16) bf16_t KV_lds[2][4][4096];  // [buf][K0,K1,V0,V1]
  __shared__ __align__(16) bf16_t P_lds[4][16*72];
  const int tid = threadIdx.x;
  const int blk = blockIdx.x;        // bh*32 + q-tile(64)
  const int qt = blk & 31;
  const int bh = blk >> 5;
  const int h = bh & 15, b = bh >> 4;
  const int wave = tid >> 6, lane = tid & 63;
  const int l15 = lane & 15, quad = lane >> 4;
  const int qhalf = wave & 1, khalf = wave >> 1;
  const int qw = qt*64 + qhalf*32;

  const bf16_t* qtb = qtT + (size_t)bh * HD * SEQ;
  const bf16_t* krb = krN + (size_t)bh * SEQ * HD;
  const bf16_t* vtb = vT  + (size_t)bh * HD * SEQ;

  // Q B-fragments (gather once per block)
  bf16x8 Qf[2][2];
  #pragma unroll
  for (int g = 0; g < 2; ++g)
    #pragma unroll
    for (int c = 0; c < 2; ++c)
      #pragma unroll
      for (int j = 0; j < 8; ++j)
        Qf[g][c][j] = qtb[(size_t)(c*32 + quad*8 + j)*SEQ + qw + g*16 + l15];

  bf16x8 ones;
  #pragma unroll
  for (int j = 0; j < 8; ++j) ones[j] = to_bf16(1.0f);

  f32x4 O[2][4] = {};
  f32x4 L[2] = {};

  // wave stages tile `wave`: 0=K half0, 1=K half1, 2=V half0, 3=V half1
  #define STAGE_KV(kt, bufIdx)                                                 \
    {                                                                          \
      const int k0 = (kt)*64;                                                  \
      bf16_t* dbase = &KV_lds[bufIdx][wave][0];                                \
      _Pragma("unroll")                                                        \
      for (int j = 0; j < 8; ++j) {                                            \
        int r = j*8 + (lane >> 3);                                             \
        int sc = (lane & 7) ^ (r & 7);                                         \
        const bf16_t* src;                                                     \
        if (wave < 2) src = krb + (size_t)(wave*1024 + k0 + r)*HD + sc*8;      \
        else          src = vtb + (size_t)r*SEQ + (wave-2)*1024 + k0 + sc*8;   \
        async_copy16(src, dbase + j*512);                                      \
      }                                                                        \
    }

  STAGE_KV(0, 0);
  __syncthreads();

  for (int kt = 0; kt < 16; ++kt) {
    const int buf = kt & 1;
    if (kt + 1 < 16) STAGE_KV(kt + 1, buf ^ 1);

    const bf16_t* Kt = &KV_lds[buf][khalf][0];
    const bf16_t* Vt = &KV_lds[buf][2 + khalf][0];
    bf16x8 ak[4][2], bv[4][2];
    #pragma unroll
    for (int nt = 0; nt < 4; ++nt)
      #pragma unroll
      for (int hh = 0; hh < 2; ++hh) {
        int idx = (nt*16 + l15)*64 + (((hh*4 + quad) ^ (l15 & 7))*8);
        ak[nt][hh] = *(const bf16x8*)&Kt[idx];
        bv[nt][hh] = *(const bf16x8*)&Vt[idx];
      }

    #pragma unroll
    for (int g = 0; g < 2; ++g) {
      f32x4 s[4] = {};
      #pragma unroll
      for (int nt = 0; nt < 4; ++nt) {
        s[nt] = MFMA16(ak[nt][0], Qf[g][0], s[nt], 0, 0, 0);
        s[nt] = MFMA16(ak[nt][1], Qf[g][1], s[nt], 0, 0, 0);
      }
      #pragma unroll
      for (int nt = 0; nt < 4; ++nt) {
        bf16x4 pk;
        #pragma unroll
        for (int r = 0; r < 4; ++r)
          pk[r] = to_bf16(__builtin_amdgcn_exp2f(s[nt][r]));
        *(bf16x4*)&P_lds[wave][l15*72 + nt*16 + quad*4] = pk;
      }
      bf16x8 ap0 = *(const bf16x8*)&P_lds[wave][l15*72 + quad*8];
      bf16x8 ap1 = *(const bf16x8*)&P_lds[wave][l15*72 + 32 + quad*8];
      #pragma unroll
      for (int nt = 0; nt < 4; ++nt) {
        O[g][nt] = MFMA16(ap0, bv[nt][0], O[g][nt], 0, 0, 0);
        O[g][nt] = MFMA16(ap1, bv[nt][1], O[g][nt], 0, 0, 0);
      }
      L[g] = MFMA16(ap0, ones, L[g], 0, 0, 0);
      L[g] = MFMA16(ap1, ones, L[g], 0, 0, 0);
    }
    __syncthreads();
  }
  #undef STAGE_KV

  // combine key-halves: waves 2,3 publish; waves 0,1 reduce + write.
  float* Os = (float*)&KV_lds[0][0][0];
  float* Ls = Os + 4096;
  if (khalf == 1) {
    int base = (qhalf*64 + lane)*32;
    #pragma unroll
    for (int g = 0; g < 2; ++g)
      #pragma unroll
      for (int nt = 0; nt < 4; ++nt)
        #pragma unroll
        for (int r = 0; r < 4; ++r)
          Os[base + g*16 + nt*4 + r] = O[g][nt][r];
    int lb = (qhalf*64 + lane)*8;
    #pragma unroll
    for (int g = 0; g < 2; ++g)
      #pragma unroll
      for (int r = 0; r < 4; ++r)
        Ls[lb + g*4 + r] = L[g][r];
  }
  __syncthreads();
  if (khalf == 0) {
    int base = (qhalf*64 + lane)*32;
    int lb = (qhalf*64 + lane)*8;
    #pragma unroll
    for (int g = 0; g < 2; ++g) {
      float lsum[4];
      #pragma unroll
      for (int r = 0; r < 4; ++r) lsum[r] = L[g][r] + Ls[lb + g*4 + r];
      #pragma unroll
      for (int nt = 0; nt < 4; ++nt)
        #pragma unroll
        for (int r = 0; r < 4; ++r) {
          float o = (O[g][nt][r] + Os[base + g*16 + nt*4 + r]) / lsum[r];
          int qrow = qw + g*16 + quad*4 + r;
          ctx[((size_t)b*SEQ + qrow)*DMODEL + h*HD + nt*16 + l15] = to_bf16(o);
        }
    }
  }
}

// ---------------------------------------------------------------------------
// K4: out = ctx @ out_w^T + bias. m-tile 128 x n-tile 64, BK=64, reg prefetch.
// ---------------------------------------------------------------------------
__global__ __launch_bounds__(256) void k4_proj(
    const bf16_t* __restrict__ ctx,    // [NB*SEQ][DMODEL] bf16
    const float* __restrict__ w,       // [DMODEL][DMODEL] fp32
    const float* __restrict__ bias,
    float* __restrict__ out)
{
  __shared__ __align__(16) bf16_t A_lds[128*72];
  __shared__ __align__(16) bf16_t B_lds[64*72];
  const int tid = threadIdx.x;
  const int blk = blockIdx.x;
  const int n0 = (blk & 15) * 64;
  const int m0 = (blk >> 4) * 128;
  const int wave = tid >> 6, lane = tid & 63;
  const int l15 = lane & 15, quad = lane >> 4;
  const int ra = tid >> 1, ca = (tid & 1) * 32;
  const int rs = tid >> 2, cs = (tid & 3) * 16;

  f32x4 acc[2][4] = {};
  bf16x8 areg[4];
  float4 wreg[4];

  #pragma unroll
  for (int i = 0; i < 4; ++i) {
    areg[i] = *(const bf16x8*)&ctx[(size_t)(m0 + ra)*DMODEL + ca + i*8];
    wreg[i] = *(const float4*)&w[(size_t)(n0 + rs)*DMODEL + cs + i*4];
  }

  for (int it = 0; it < DMODEL/64; ++it) {
    if (it) __syncthreads();
    #pragma unroll
    for (int i = 0; i < 4; ++i)
      *(bf16x8*)&A_lds[ra*72 + ca + i*8] = areg[i];
    #pragma unroll
    for (int i = 0; i < 2; ++i) {
      bf16x8 wb;
      float4 wa = wreg[i*2], wc = wreg[i*2+1];
      wb[0]=to_bf16(wa.x); wb[1]=to_bf16(wa.y); wb[2]=to_bf16(wa.z); wb[3]=to_bf16(wa.w);
      wb[4]=to_bf16(wc.x); wb[5]=to_bf16(wc.y); wb[6]=to_bf16(wc.z); wb[7]=to_bf16(wc.w);
      *(bf16x8*)&B_lds[rs*72 + cs + i*8] = wb;
    }
    __syncthreads();
    if (it + 1 < DMODEL/64) {
      int kb = (it + 1) * 64;
      #pragma unroll
      for (int i = 0; i < 4; ++i) {
        areg[i] = *(const bf16x8*)&ctx[(size_t)(m0 + ra)*DMODEL + kb + ca + i*8];
        wreg[i] = *(const float4*)&w[(size_t)(n0 + rs)*DMODEL + kb + cs + i*4];
      }
    }
    #pragma unroll
    for (int kc = 0; kc < 2; ++kc) {
      const int off = kc*32 + quad*8;
      bf16x8 bfr[4];
      #pragma unroll
      for (int nt = 0; nt < 4; ++nt)
        bfr[nt] = *(const bf16x8*)&B_lds[(nt*16 + l15)*72 + off];
      #pragma unroll
      for (int g = 0; g < 2; ++g) {
        bf16x8 af = *(const bf16x8*)&A_lds[(wave*32 + g*16 + l15)*72 + off];
        #pragma unroll
        for (int nt = 0; nt < 4; ++nt)
          acc[g][nt] = MFMA16(af, bfr[nt], acc[g][nt], 0, 0, 0);
      }
    }
  }
  #pragma unroll
  for (int nt = 0; nt < 4; ++nt) {
    float bb = bias[n0 + nt*16 + l15];
    #pragma unroll
    for (int g = 0; g < 2; ++g)
      #pragma unroll
      for (int r = 0; r < 4; ++r)
        out[(size_t)(m0 + wave*32 + g*16 + quad*4 + r)*DMODEL + n0 + nt*16 + l15] =
            acc[g][nt][r] + bb;
  }
}

extern "C" void kernel_launch(void* const* d_in, const int* in_sizes, int n_in,
                              void* d_out, int out_size, void* d_ws, size_t ws_size,
                              hipStream_t stream)
{
  const float* q     = (const float*)d_in[0];
  const float* k     = (const float*)d_in[1];
  const float* v     = (const float*)d_in[2];
  const float* mask  = (const float*)d_in[3];
  const float* out_w = (const float*)d_in[4];
  const float* out_b = (const float*)d_in[5];
  float* out = (float*)d_out;

  const size_t elems = (size_t)NB * NH * SEQ * HD;
  bf16_t* qrT = (bf16_t*)d_ws;
  bf16_t* krN = qrT + elems;
  bf16_t* vT  = krN + elems;
  bf16_t* qtT = vT  + elems;
  bf16_t* ctx = qtT + elems;

  k1_rope_pack<<<dim3(NB*NH*(SEQ/64)), dim3(256), 0, stream>>>(q, k, v, qrT, krN, vT);
  k2_qt_gemm <<<dim3(NH*(SEQ/32)),     dim3(256), 0, stream>>>(mask, qrT, qtT);
  k3_flash   <<<dim3(NB*NH*(SEQ/64)),  dim3(256), 0, stream>>>(qtT, krN, vT, ctx);
  k4_proj    <<<dim3((NB*SEQ/128)*(DMODEL/64)), dim3(256), 0, stream>>>(ctx, out_w, out_b, out);
}